// Round 6
// baseline (158.268 us; speedup 1.0000x reference)
//
#include <hip/hip_runtime.h>
#include <math.h>

#define MPTS 8192
#define DIMS 32

typedef __bf16 bf16x8 __attribute__((ext_vector_type(8)));
typedef float  f32x4  __attribute__((ext_vector_type(4)));

// Insert v into sorted-DESCENDING top-4 (t0>=t1>=t2>=t3): 1 max + 3 med3.
__device__ __forceinline__ void top4L_insert(float v, float& t0, float& t1, float& t2, float& t3) {
    float n0 = fmaxf(t0, v);
    float n1 = __builtin_amdgcn_fmed3f(v, t0, t1);
    float n2 = __builtin_amdgcn_fmed3f(v, t1, t2);
    float n3 = __builtin_amdgcn_fmed3f(v, t2, t3);
    t0 = n0; t1 = n1; t2 = n2; t3 = n3;
}

__device__ __forceinline__ unsigned short f32_to_bf16_rne(float x) {
    unsigned u = __float_as_uint(x);
    unsigned r = u + 0x7FFFu + ((u >> 16) & 1u);
    return (unsigned short)(r >> 16);
}

// K1: bf16 conversion of P,Q + norms pre-scaled by -0.5 ( -|x|^2/2 ).
__global__ void prep_kernel(const float* __restrict__ P, const float* __restrict__ Q,
                            unsigned short* __restrict__ Phi, unsigned short* __restrict__ Qhi,
                            float* __restrict__ normP, float* __restrict__ normQ) {
    int t = blockIdx.x * 256 + threadIdx.x;          // 0 .. 65535
    int mat = t >> 15;                               // 0 = P, 1 = Q
    int idx = t & 32767;
    int r = idx >> 2, seg = idx & 3;                 // 8 elements per thread
    const float* X = mat ? Q : P;
    unsigned short* Xhi = mat ? Qhi : Phi;
    float* nX = mat ? normQ : normP;

    const float* src = X + (size_t)r * DIMS + seg * 8;
    float4 v0 = *(const float4*)(src);
    float4 v1 = *(const float4*)(src + 4);
    float f[8] = {v0.x, v0.y, v0.z, v0.w, v1.x, v1.y, v1.z, v1.w};

    float p = 0.f;
#pragma unroll
    for (int k = 0; k < 8; ++k) p = fmaf(f[k], f[k], p);
    p += __shfl_xor(p, 1);
    p += __shfl_xor(p, 2);      // seg groups of 4 are lane-aligned
    if (seg == 0) nX[r] = -0.5f * p;

    unsigned short h[8];
#pragma unroll
    for (int k = 0; k < 8; ++k) h[k] = f32_to_bf16_rne(f[k]);
    uint4 ph;
    ph.x = (unsigned)h[0] | ((unsigned)h[1] << 16);
    ph.y = (unsigned)h[2] | ((unsigned)h[3] << 16);
    ph.z = (unsigned)h[4] | ((unsigned)h[5] << 16);
    ph.w = (unsigned)h[6] | ((unsigned)h[7] << 16);
    *(uint4*)(Xhi + (size_t)r * DIMS + seg * 8) = ph;
}

// K2: fused knn+count. grid (MPTS/16, 2 dirs), block = 512 thr = 8 waves.
// Block owns 16 queries (rows of Y). Phase 1: scan all 8192 rows of Y
// (wave w gets [w*1024,(w+1)*1024)), top-4 in s-domain (s = dot - na/2;
// larger == closer; per-query shift nb is a ranking-exact constant).
// Block merge -> nu^2 + s-domain tau. Phase 2: scan all 8192 rows of X,
// count s >= tau. Direct stores: each query owned by exactly one block.
__global__ __launch_bounds__(512, 4)
void fused_kernel(const unsigned short* __restrict__ Phi, const unsigned short* __restrict__ Qhi,
                  const float* __restrict__ normP, const float* __restrict__ normQ,
                  float* __restrict__ nusqP, float* __restrict__ nusqQ,
                  int* __restrict__ countP, int* __restrict__ countQ) {
    __shared__ float ldsM[16 * 32 * 4];   // 8 KB: [query][list][4]
    __shared__ float ldsM2[16 * 8 * 4];   // 2 KB
    __shared__ float ldsTau[16];
    __shared__ int   ldsC[16 * 32];       // 2 KB
    const unsigned short *Yhi, *Xhi; const float *nY, *nX; float* nusqOut; int* cntOut;
    if (blockIdx.y == 0) { Yhi = Qhi; nY = normQ; Xhi = Phi; nX = normP;
                           nusqOut = nusqQ; cntOut = countQ; }   // k_p for div_p
    else                 { Yhi = Phi; nY = normP; Xhi = Qhi; nX = normQ;
                           nusqOut = nusqP; cntOut = countP; }
    const int tid = threadIdx.x;
    const int w = tid >> 6, l = tid & 63, q = l & 15, quad = l >> 4;
    const int q0 = blockIdx.x * 16;

    // B-frag: 16 query rows; n = lane&15, k-octet = lane>>4
    bf16x8 bh = *(const bf16x8*)(Yhi + (size_t)(q0 + q) * DIMS + quad * 8);

    // ---------- phase 1: knn over Y ----------
    float t0 = -3.4e38f, t1 = t0, t2 = t0, t3 = t0;
    {
        const unsigned short* pH = Yhi + ((size_t)(w * 1024) + q) * DIMS + quad * 8;
        const float* pN = nY + w * 1024 + quad * 4;
        for (int i = 0; i < 32; ++i) {
            bf16x8 ah0 = *(const bf16x8*)(pH);
            float4 nA0 = *(const float4*)(pN);
            bf16x8 ah1 = *(const bf16x8*)(pH + 16 * DIMS);
            float4 nA1 = *(const float4*)(pN + 16);
            pH += 32 * DIMS; pN += 32;
            f32x4 c0v = {nA0.x, nA0.y, nA0.z, nA0.w};
            f32x4 c1v = {nA1.x, nA1.y, nA1.z, nA1.w};
            f32x4 a0 = __builtin_amdgcn_mfma_f32_16x16x32_bf16(ah0, bh, c0v, 0, 0, 0);
            f32x4 a1 = __builtin_amdgcn_mfma_f32_16x16x32_bf16(ah1, bh, c1v, 0, 0, 0);
#pragma unroll
            for (int r = 0; r < 4; ++r) top4L_insert(a0[r], t0, t1, t2, t3);
#pragma unroll
            for (int r = 0; r < 4; ++r) top4L_insert(a1[r], t0, t1, t2, t3);
        }
    }
    // block merge: 32 lists per query -> tau
    *(float4*)&ldsM[(q * 32 + (w * 4 + quad)) * 4] = make_float4(t0, t1, t2, t3);
    __syncthreads();
    if (tid < 128) {
        int qq = tid >> 3, c = tid & 7;
        float a0 = -3.4e38f, a1 = a0, a2 = a0, a3 = a0;
        const float* src = &ldsM[(qq * 32 + c * 4) * 4];
#pragma unroll
        for (int s = 0; s < 16; ++s) top4L_insert(src[s], a0, a1, a2, a3);
        *(float4*)&ldsM2[(qq * 8 + c) * 4] = make_float4(a0, a1, a2, a3);
    }
    __syncthreads();
    if (tid < 16) {
        float a0 = -3.4e38f, a1 = a0, a2 = a0, a3 = a0;
        const float* src = &ldsM2[tid * 32];
#pragma unroll
        for (int s = 0; s < 32; ++s) top4L_insert(src[s], a0, a1, a2, a3);
        float nb = -2.0f * nY[q0 + tid];               // |y|^2
        float nu2 = fmaxf(nb - 2.0f * a3, 1e-12f);     // sq-domain nu^2, clamped
        nusqOut[q0 + tid] = nu2;
        ldsTau[tid] = 0.5f * (nb - nu2);               // s-domain threshold
    }
    __syncthreads();
    const float tau = ldsTau[q];

    // ---------- phase 2: count over X ----------
    int cnt = 0;
    {
        const unsigned short* pH = Xhi + ((size_t)(w * 1024) + q) * DIMS + quad * 8;
        const float* pN = nX + w * 1024 + quad * 4;
        for (int i = 0; i < 32; ++i) {
            bf16x8 ah0 = *(const bf16x8*)(pH);
            float4 nA0 = *(const float4*)(pN);
            bf16x8 ah1 = *(const bf16x8*)(pH + 16 * DIMS);
            float4 nA1 = *(const float4*)(pN + 16);
            pH += 32 * DIMS; pN += 32;
            f32x4 c0v = {nA0.x, nA0.y, nA0.z, nA0.w};
            f32x4 c1v = {nA1.x, nA1.y, nA1.z, nA1.w};
            f32x4 a0 = __builtin_amdgcn_mfma_f32_16x16x32_bf16(ah0, bh, c0v, 0, 0, 0);
            f32x4 a1 = __builtin_amdgcn_mfma_f32_16x16x32_bf16(ah1, bh, c1v, 0, 0, 0);
#pragma unroll
            for (int r = 0; r < 4; ++r) {
                cnt += (a0[r] >= tau) ? 1 : 0;
                cnt += (a1[r] >= tau) ? 1 : 0;
            }
        }
    }
    ldsC[q * 32 + (w * 4 + quad)] = cnt;
    __syncthreads();
    if (tid < 16) {
        int s = 0;
#pragma unroll
        for (int u = 0; u < 32; ++u) s += ldsC[tid * 32 + u];
        cntOut[q0 + tid] = s;
    }
}

// K3: epilogue with wave-shuffle reductions (exact fp32 clip/pow semantics).
__global__ __launch_bounds__(512)
void final_kernel(const int* __restrict__ countP, const int* __restrict__ countQ,
                  const float* __restrict__ nusqP, const float* __restrict__ nusqQ,
                  float* __restrict__ out) {
    __shared__ int    riQ[8], riP[8];
    __shared__ double rdQ[8], rdP[8];
    const int tid = threadIdx.x;
    const int w = tid >> 6, l = tid & 63;

    int sQ = 0, sP = 0;
    for (int j = tid; j < MPTS; j += 512) { sQ += countQ[j]; sP += countP[j]; }
#pragma unroll
    for (int o = 32; o > 0; o >>= 1) { sQ += __shfl_down(sQ, o); sP += __shfl_down(sP, o); }
    if (l == 0) { riQ[w] = sQ; riP[w] = sP; }
    __syncthreads();
    int totQ = 0, totP = 0;
#pragma unroll
    for (int u = 0; u < 8; ++u) { totQ += riQ[u]; totP += riP[u]; }

    const float kq_term = 3.0f / 24576.0f;
    float kpQ = (float)totQ + 1e-20f;
    float kpP = (float)totP + 1e-20f;
    double rQ = 0.0, rP = 0.0;
    for (int j = tid; j < MPTS; j += 512) {
        {
            float nu = sqrtf(nusqQ[j]);
            float x = nu * nu; x *= x; x *= x; x *= x; x *= x;   // nu^32
            float inv = 1.0f / (x + 1e-20f);
            float p_den = ((float)countQ[j] / kpQ) * inv;
            p_den = fminf(fmaxf(p_den, 1e-20f), 1e10f);
            float q_den = kq_term * inv;
            q_den = fminf(fmaxf(q_den, 1e-20f), 1e10f);
            rQ += (double)((p_den / q_den) * kq_term);
        }
        {
            float nu = sqrtf(nusqP[j]);
            float x = nu * nu; x *= x; x *= x; x *= x; x *= x;
            float inv = 1.0f / (x + 1e-20f);
            float p_den = ((float)countP[j] / kpP) * inv;
            p_den = fminf(fmaxf(p_den, 1e-20f), 1e10f);
            float q_den = kq_term * inv;
            q_den = fminf(fmaxf(q_den, 1e-20f), 1e10f);
            rP += (double)((p_den / q_den) * kq_term);
        }
    }
#pragma unroll
    for (int o = 32; o > 0; o >>= 1) { rQ += __shfl_down(rQ, o); rP += __shfl_down(rP, o); }
    if (l == 0) { rdQ[w] = rQ; rdP[w] = rP; }
    __syncthreads();
    if (tid == 0) {
        double RQ = 0.0, RP = 0.0;
#pragma unroll
        for (int u = 0; u < 8; ++u) { RQ += rdQ[u]; RP += rdP[u]; }
        float divP = fmaxf(0.0f, logf((float)RQ));    // alpha=2 -> 1/(alpha-1)=1
        float divQ = fmaxf(0.0f, logf((float)RP));
        out[0] = fmaxf(divP, divQ);
    }
}

extern "C" void kernel_launch(void* const* d_in, const int* in_sizes, int n_in,
                              void* d_out, int out_size, void* d_ws, size_t ws_size,
                              hipStream_t stream) {
    const float* P = (const float*)d_in[0];
    const float* Q = (const float*)d_in[1];
    float* out = (float*)d_out;

    unsigned short* Phi = (unsigned short*)d_ws;
    unsigned short* Qhi = Phi + MPTS * DIMS;
    float* normP = (float*)(Qhi + MPTS * DIMS);
    float* normQ = normP + MPTS;
    float* nusqP = normQ + MPTS;
    float* nusqQ = nusqP + MPTS;
    int* countP  = (int*)(nusqQ + MPTS);
    int* countQ  = countP + MPTS;

    prep_kernel<<<256, 256, 0, stream>>>(P, Q, Phi, Qhi, normP, normQ);
    fused_kernel<<<dim3(MPTS / 16, 2), 512, 0, stream>>>(Phi, Qhi, normP, normQ,
                                                         nusqP, nusqQ, countP, countQ);
    final_kernel<<<1, 512, 0, stream>>>(countP, countQ, nusqP, nusqQ, out);
}

// Round 7
// 110.918 us; speedup vs baseline: 1.4269x; 1.4269x over previous
//
#include <hip/hip_runtime.h>
#include <math.h>

#define MPTS 8192
#define DIMS 32
#define QB   64      // queries per block
#define NW   16      // waves per block (1024 threads)

typedef __bf16 bf16x8 __attribute__((ext_vector_type(8)));
typedef float  f32x4  __attribute__((ext_vector_type(4)));

// Insert v into sorted-DESCENDING top-4 (t0>=t1>=t2>=t3): 1 max + 3 med3.
__device__ __forceinline__ void top4L_insert(float v, float& t0, float& t1, float& t2, float& t3) {
    float n0 = fmaxf(t0, v);
    float n1 = __builtin_amdgcn_fmed3f(v, t0, t1);
    float n2 = __builtin_amdgcn_fmed3f(v, t1, t2);
    float n3 = __builtin_amdgcn_fmed3f(v, t2, t3);
    t0 = n0; t1 = n1; t2 = n2; t3 = n3;
}

__device__ __forceinline__ unsigned short f32_to_bf16_rne(float x) {
    unsigned u = __float_as_uint(x);
    unsigned r = u + 0x7FFFu + ((u >> 16) & 1u);
    return (unsigned short)(r >> 16);
}

// K1: bf16 conversion of P,Q + norms pre-scaled by -0.5 ( -|x|^2/2 ).
__global__ void prep_kernel(const float* __restrict__ P, const float* __restrict__ Q,
                            unsigned short* __restrict__ Phi, unsigned short* __restrict__ Qhi,
                            float* __restrict__ normP, float* __restrict__ normQ) {
    int t = blockIdx.x * 256 + threadIdx.x;          // 0 .. 65535
    int mat = t >> 15;                               // 0 = P, 1 = Q
    int idx = t & 32767;
    int r = idx >> 2, seg = idx & 3;                 // 8 elements per thread
    const float* X = mat ? Q : P;
    unsigned short* Xhi = mat ? Qhi : Phi;
    float* nX = mat ? normQ : normP;

    const float* src = X + (size_t)r * DIMS + seg * 8;
    float4 v0 = *(const float4*)(src);
    float4 v1 = *(const float4*)(src + 4);
    float f[8] = {v0.x, v0.y, v0.z, v0.w, v1.x, v1.y, v1.z, v1.w};

    float p = 0.f;
#pragma unroll
    for (int k = 0; k < 8; ++k) p = fmaf(f[k], f[k], p);
    p += __shfl_xor(p, 1);
    p += __shfl_xor(p, 2);      // seg groups of 4 are lane-aligned
    if (seg == 0) nX[r] = -0.5f * p;

    unsigned short h[8];
#pragma unroll
    for (int k = 0; k < 8; ++k) h[k] = f32_to_bf16_rne(f[k]);
    uint4 ph;
    ph.x = (unsigned)h[0] | ((unsigned)h[1] << 16);
    ph.y = (unsigned)h[2] | ((unsigned)h[3] << 16);
    ph.z = (unsigned)h[4] | ((unsigned)h[5] << 16);
    ph.w = (unsigned)h[6] | ((unsigned)h[7] << 16);
    *(uint4*)(Xhi + (size_t)r * DIMS + seg * 8) = ph;
}

// K2: fused knn+count. grid (MPTS/QB, 2 dirs), block = 1024 thr = 16 waves,
// 1 block/CU. Block owns 64 queries; each lane holds 4 B-frags (queries
// q, q+16, q+32, q+48) -> 4 independent top-4 chains. Wave w scans candidate
// rows [w*512,(w+1)*512): per iter 2 A-row loads feed 8 MFMAs -> 32 inserts.
// s-domain: s = dot - na/2 (larger == closer; per-query shift is constant).
// Phase 2 re-scans the other matrix counting s >= tau. Direct stores.
__global__ __launch_bounds__(1024, 4)
void fused_kernel(const unsigned short* __restrict__ Phi, const unsigned short* __restrict__ Qhi,
                  const float* __restrict__ normP, const float* __restrict__ normQ,
                  float* __restrict__ nusqP, float* __restrict__ nusqQ,
                  int* __restrict__ countP, int* __restrict__ countQ) {
    __shared__ float ldsM[QB * 64 * 4];   // 64 KB: [query][list][4]
    __shared__ float ldsM2[QB * 8 * 4];   // 8 KB
    __shared__ float ldsTau[QB];
    __shared__ int   ldsC[QB * 64];       // 16 KB
    const unsigned short *Yhi, *Xhi; const float *nY, *nX; float* nusqOut; int* cntOut;
    if (blockIdx.y == 0) { Yhi = Qhi; nY = normQ; Xhi = Phi; nX = normP;
                           nusqOut = nusqQ; cntOut = countQ; }   // k_p for div_p
    else                 { Yhi = Phi; nY = normP; Xhi = Qhi; nX = normQ;
                           nusqOut = nusqP; cntOut = countP; }
    const int tid = threadIdx.x;
    const int w = tid >> 6, l = tid & 63, q = l & 15, quad = l >> 4;
    const int q0 = blockIdx.x * QB;

    // 4 B-frags: query rows q0 + 16*b + q; k-octet = quad
    bf16x8 bh[4];
#pragma unroll
    for (int b = 0; b < 4; ++b)
        bh[b] = *(const bf16x8*)(Yhi + (size_t)(q0 + b * 16 + q) * DIMS + quad * 8);

    // ---------- phase 1: knn over Y ----------
    float t0[4], t1[4], t2[4], t3[4];
#pragma unroll
    for (int b = 0; b < 4; ++b) t0[b] = t1[b] = t2[b] = t3[b] = -3.4e38f;
    {
        const unsigned short* pH = Yhi + ((size_t)(w * 512) + q) * DIMS + quad * 8;
        const float* pN = nY + w * 512 + quad * 4;
        for (int i = 0; i < 16; ++i) {
            bf16x8 ah0 = *(const bf16x8*)(pH);
            float4 nA0 = *(const float4*)(pN);
            bf16x8 ah1 = *(const bf16x8*)(pH + 16 * DIMS);
            float4 nA1 = *(const float4*)(pN + 16);
            pH += 32 * DIMS; pN += 32;
            f32x4 c0v = {nA0.x, nA0.y, nA0.z, nA0.w};
            f32x4 c1v = {nA1.x, nA1.y, nA1.z, nA1.w};
#pragma unroll
            for (int b = 0; b < 4; ++b) {
                f32x4 a0 = __builtin_amdgcn_mfma_f32_16x16x32_bf16(ah0, bh[b], c0v, 0, 0, 0);
                f32x4 a1 = __builtin_amdgcn_mfma_f32_16x16x32_bf16(ah1, bh[b], c1v, 0, 0, 0);
#pragma unroll
                for (int r = 0; r < 4; ++r) top4L_insert(a0[r], t0[b], t1[b], t2[b], t3[b]);
#pragma unroll
                for (int r = 0; r < 4; ++r) top4L_insert(a1[r], t0[b], t1[b], t2[b], t3[b]);
            }
        }
    }
    // block merge: 64 lists per query -> tau
#pragma unroll
    for (int b = 0; b < 4; ++b)
        *(float4*)&ldsM[((q + b * 16) * 64 + (w * 4 + quad)) * 4] =
            make_float4(t0[b], t1[b], t2[b], t3[b]);
    __syncthreads();
    if (tid < 512) {
        int qq = tid >> 3, c = tid & 7;                 // 8 chunks of 8 lists
        float a0 = -3.4e38f, a1 = a0, a2 = a0, a3 = a0;
        const float* src = &ldsM[(qq * 64 + c * 8) * 4];
#pragma unroll
        for (int s = 0; s < 32; ++s) top4L_insert(src[s], a0, a1, a2, a3);
        *(float4*)&ldsM2[(qq * 8 + c) * 4] = make_float4(a0, a1, a2, a3);
    }
    __syncthreads();
    if (tid < QB) {
        float a0 = -3.4e38f, a1 = a0, a2 = a0, a3 = a0;
        const float* src = &ldsM2[tid * 32];
#pragma unroll
        for (int s = 0; s < 32; ++s) top4L_insert(src[s], a0, a1, a2, a3);
        float nb = -2.0f * nY[q0 + tid];               // |y|^2
        float nu2 = fmaxf(nb - 2.0f * a3, 1e-12f);     // sq-domain nu^2, clamped
        nusqOut[q0 + tid] = nu2;
        ldsTau[tid] = 0.5f * (nb - nu2);               // s-domain threshold
    }
    __syncthreads();
    float tau[4];
#pragma unroll
    for (int b = 0; b < 4; ++b) tau[b] = ldsTau[q + b * 16];

    // ---------- phase 2: count over X ----------
    int cnt[4] = {0, 0, 0, 0};
    {
        const unsigned short* pH = Xhi + ((size_t)(w * 512) + q) * DIMS + quad * 8;
        const float* pN = nX + w * 512 + quad * 4;
        for (int i = 0; i < 16; ++i) {
            bf16x8 ah0 = *(const bf16x8*)(pH);
            float4 nA0 = *(const float4*)(pN);
            bf16x8 ah1 = *(const bf16x8*)(pH + 16 * DIMS);
            float4 nA1 = *(const float4*)(pN + 16);
            pH += 32 * DIMS; pN += 32;
            f32x4 c0v = {nA0.x, nA0.y, nA0.z, nA0.w};
            f32x4 c1v = {nA1.x, nA1.y, nA1.z, nA1.w};
#pragma unroll
            for (int b = 0; b < 4; ++b) {
                f32x4 a0 = __builtin_amdgcn_mfma_f32_16x16x32_bf16(ah0, bh[b], c0v, 0, 0, 0);
                f32x4 a1 = __builtin_amdgcn_mfma_f32_16x16x32_bf16(ah1, bh[b], c1v, 0, 0, 0);
#pragma unroll
                for (int r = 0; r < 4; ++r) {
                    cnt[b] += (a0[r] >= tau[b]) ? 1 : 0;
                    cnt[b] += (a1[r] >= tau[b]) ? 1 : 0;
                }
            }
        }
    }
#pragma unroll
    for (int b = 0; b < 4; ++b) ldsC[(q + b * 16) * 64 + (w * 4 + quad)] = cnt[b];
    __syncthreads();
    if (tid < QB) {
        int s = 0;
#pragma unroll
        for (int u = 0; u < 64; ++u) s += ldsC[tid * 64 + u];
        cntOut[q0 + tid] = s;
    }
}

// K3: epilogue with wave-shuffle reductions (exact fp32 clip/pow semantics).
__global__ __launch_bounds__(512)
void final_kernel(const int* __restrict__ countP, const int* __restrict__ countQ,
                  const float* __restrict__ nusqP, const float* __restrict__ nusqQ,
                  float* __restrict__ out) {
    __shared__ int    riQ[8], riP[8];
    __shared__ double rdQ[8], rdP[8];
    const int tid = threadIdx.x;
    const int w = tid >> 6, l = tid & 63;

    int sQ = 0, sP = 0;
    for (int j = tid; j < MPTS; j += 512) { sQ += countQ[j]; sP += countP[j]; }
#pragma unroll
    for (int o = 32; o > 0; o >>= 1) { sQ += __shfl_down(sQ, o); sP += __shfl_down(sP, o); }
    if (l == 0) { riQ[w] = sQ; riP[w] = sP; }
    __syncthreads();
    int totQ = 0, totP = 0;
#pragma unroll
    for (int u = 0; u < 8; ++u) { totQ += riQ[u]; totP += riP[u]; }

    const float kq_term = 3.0f / 24576.0f;
    float kpQ = (float)totQ + 1e-20f;
    float kpP = (float)totP + 1e-20f;
    double rQ = 0.0, rP = 0.0;
    for (int j = tid; j < MPTS; j += 512) {
        {
            float nu = sqrtf(nusqQ[j]);
            float x = nu * nu; x *= x; x *= x; x *= x; x *= x;   // nu^32
            float inv = 1.0f / (x + 1e-20f);
            float p_den = ((float)countQ[j] / kpQ) * inv;
            p_den = fminf(fmaxf(p_den, 1e-20f), 1e10f);
            float q_den = kq_term * inv;
            q_den = fminf(fmaxf(q_den, 1e-20f), 1e10f);
            rQ += (double)((p_den / q_den) * kq_term);
        }
        {
            float nu = sqrtf(nusqP[j]);
            float x = nu * nu; x *= x; x *= x; x *= x; x *= x;
            float inv = 1.0f / (x + 1e-20f);
            float p_den = ((float)countP[j] / kpP) * inv;
            p_den = fminf(fmaxf(p_den, 1e-20f), 1e10f);
            float q_den = kq_term * inv;
            q_den = fminf(fmaxf(q_den, 1e-20f), 1e10f);
            rP += (double)((p_den / q_den) * kq_term);
        }
    }
#pragma unroll
    for (int o = 32; o > 0; o >>= 1) { rQ += __shfl_down(rQ, o); rP += __shfl_down(rP, o); }
    if (l == 0) { rdQ[w] = rQ; rdP[w] = rP; }
    __syncthreads();
    if (tid == 0) {
        double RQ = 0.0, RP = 0.0;
#pragma unroll
        for (int u = 0; u < 8; ++u) { RQ += rdQ[u]; RP += rdP[u]; }
        float divP = fmaxf(0.0f, logf((float)RQ));    // alpha=2 -> 1/(alpha-1)=1
        float divQ = fmaxf(0.0f, logf((float)RP));
        out[0] = fmaxf(divP, divQ);
    }
}

extern "C" void kernel_launch(void* const* d_in, const int* in_sizes, int n_in,
                              void* d_out, int out_size, void* d_ws, size_t ws_size,
                              hipStream_t stream) {
    const float* P = (const float*)d_in[0];
    const float* Q = (const float*)d_in[1];
    float* out = (float*)d_out;

    unsigned short* Phi = (unsigned short*)d_ws;
    unsigned short* Qhi = Phi + MPTS * DIMS;
    float* normP = (float*)(Qhi + MPTS * DIMS);
    float* normQ = normP + MPTS;
    float* nusqP = normQ + MPTS;
    float* nusqQ = nusqP + MPTS;
    int* countP  = (int*)(nusqQ + MPTS);
    int* countQ  = countP + MPTS;

    prep_kernel<<<256, 256, 0, stream>>>(P, Q, Phi, Qhi, normP, normQ);
    fused_kernel<<<dim3(MPTS / QB, 2), 1024, 0, stream>>>(Phi, Qhi, normP, normQ,
                                                          nusqP, nusqQ, countP, countQ);
    final_kernel<<<1, 512, 0, stream>>>(countP, countQ, nusqP, nusqQ, out);
}